// Round 6
// baseline (790.838 us; speedup 1.0000x reference)
//
#include <hip/hip_runtime.h>
#include <hip/hip_bf16.h>

#define BATCH 16
#define NN 1024
#define MM 1024
#define DD 512

#define LOG2E 1.4426950408889634f
#define LN2f  0.6931471805599453f
#define NEGS  -1.442695e9f   // NEG (-1e9) scaled by log2e; acts as -inf sentinel

// nw_dp geometry: 16 blocks x 512 thr = 8 waves/batch (2 waves/SIMD), lane
// owns 2 rows x 4 cols per iteration. NO __syncthreads in the main loop:
// adjacent waves sync point-to-point via LDS seq/prog flags, so the two
// waves sharing a SIMD never sleep on each other's barrier (round-2 showed
// independent SIMD-mates reach ~57% issue util vs ~40% barrier-coupled).
// DSTAG = 63*4 + 4*8 = 284 (8-iteration natural slack, spin covers jitter).
// Ring = 256 slots x 4 cols; WAR backpressure caps producer lead at ~224.
#define WAVES 8
#define DSTAG 284
#define PF    4               // theta prefetch depth (iterations)
#define GTOT  816             // g_last = (1020 + 7*284 + 252)/4 = 815; mult of 4

typedef __bf16 v8bf __attribute__((ext_vector_type(8)));
typedef __bf16 v4bf __attribute__((ext_vector_type(4)));
typedef float  v4f  __attribute__((ext_vector_type(4)));

// ---------------------------------------------------------------- zero A acc
__global__ void zero_acc(float* a) {
    if (threadIdx.x < BATCH) a[threadIdx.x] = 0.0f;
}

// ------------------------------------------- fp32->bf16 convert + gap-dot
__global__ __launch_bounds__(256) void conv_reduce(
        const float* __restrict__ zx, const float* __restrict__ zy,
        const float* __restrict__ gw,
        __bf16* __restrict__ zxb, __bf16* __restrict__ zyb,
        float* __restrict__ acc) {
    const int chunk = blockIdx.x, b = blockIdx.y, which = blockIdx.z;
    const float* src = which ? zy : zx;
    __bf16* dst = which ? zyb : zxb;
    const float* g = gw + which * DD;
    const size_t base = ((size_t)b * NN + (size_t)chunk * 64) * DD;
    const int t = threadIdx.x;
    const int col = (t * 4) & (DD - 1);
    const float4 gv = *(const float4*)(g + col);
    float sum = 0.0f;
    #pragma unroll 4
    for (int it = 0; it < 32; ++it) {
        size_t off = base + (size_t)it * 1024 + t * 4;
        float4 x = *(const float4*)(src + off);
        sum += x.x * gv.x + x.y * gv.y + x.z * gv.z + x.w * gv.w;
        v4bf o = { (__bf16)x.x, (__bf16)x.y, (__bf16)x.z, (__bf16)x.w };
        *(v4bf*)(dst + off) = o;
    }
    #pragma unroll
    for (int o = 32; o > 0; o >>= 1) sum += __shfl_down(sum, o);
    __shared__ float wsum[4];
    if ((t & 63) == 0) wsum[t >> 6] = sum;
    __syncthreads();
    if (t == 0) {
        float s = wsum[0] + wsum[1] + wsum[2] + wsum[3];
        atomicAdd(acc + b, s * (1.0f / 1024.0f));
    }
}

// ------------------------------------------------------- bf16 MFMA NT GEMM
// m97-structure: 128x128 tile, 4 waves 2x2, 4x4 16x16x32 MFMA frags, BK=32,
// global_load_lds width 16, linear LDS. out = theta^T via swapped args.
__global__ __launch_bounds__(256) void gemm_bt(
        const __bf16* __restrict__ Abf, const __bf16* __restrict__ Bbf,
        float* __restrict__ theta) {
    __shared__ __bf16 As[128 * 32];
    __shared__ __bf16 Bs[128 * 32];
    const int b = blockIdx.z;
    const int i0 = blockIdx.y * 128, j0 = blockIdx.x * 128;
    const __bf16* ap = Abf + ((size_t)b * NN + i0) * DD;
    const __bf16* bp = Bbf + ((size_t)b * MM + j0) * DD;
    const int t = threadIdx.x;
    const int lane = t & 63, wave = t >> 6;
    const int wr = wave >> 1, wc = wave & 1;
    const int mrow = lane & 15, quad = lane >> 4;
    const int arow = wave * 32 + (lane >> 2);
    const int acol = (lane & 3) * 8;
    v4f acc[4][4] = {};
    for (int kk = 0; kk < DD; kk += 32) {
        __syncthreads();
        #pragma unroll
        for (int i = 0; i < 2; ++i) {
            const __bf16* ga = ap + (size_t)(arow + 16 * i) * DD + kk + acol;
            const __bf16* gb = bp + (size_t)(arow + 16 * i) * DD + kk + acol;
            __builtin_amdgcn_global_load_lds(
                (const __attribute__((address_space(1))) void*)ga,
                (__attribute__((address_space(3))) void*)(As + wave * 1024 + i * 512),
                16, 0, 0);
            __builtin_amdgcn_global_load_lds(
                (const __attribute__((address_space(1))) void*)gb,
                (__attribute__((address_space(3))) void*)(Bs + wave * 1024 + i * 512),
                16, 0, 0);
        }
        __syncthreads();
        v8bf af[4];
        #pragma unroll
        for (int m = 0; m < 4; ++m)
            af[m] = *(const v8bf*)&As[(wr * 64 + m * 16 + mrow) * 32 + quad * 8];
        #pragma unroll
        for (int n = 0; n < 4; ++n) {
            v8bf bf = *(const v8bf*)&Bs[(wc * 64 + n * 16 + mrow) * 32 + quad * 8];
            #pragma unroll
            for (int m = 0; m < 4; ++m)
                acc[m][n] = __builtin_amdgcn_mfma_f32_16x16x32_bf16(af[m], bf, acc[m][n], 0, 0, 0);
        }
    }
    const size_t tb = (size_t)b * NN * MM;
    #pragma unroll
    for (int n = 0; n < 4; ++n) {
        int j = j0 + wc * 64 + n * 16 + mrow;
        #pragma unroll
        for (int m = 0; m < 4; ++m) {
            #pragma unroll
            for (int r = 0; r < 4; ++r) {
                int i = i0 + wr * 64 + m * 16 + quad * 4 + r;
                theta[tb + (size_t)i * MM + j] = acc[m][n][r];
            }
        }
    }
}

// --------------------------------------------------- soft-NW wavefront DP
// 8 waves per batch (512 threads). Wave w owns V-rows 128w+1..128w+128, lane
// owns 2 rows x 4 cols per iteration (same proven cell/fixup structure as
// rounds 3/5, R narrowed 4->2 to double wave count).
// P2P sync protocol (NO block barrier in loop):
//  producer (lane 63, wave w<7): ring[w][slot] = s0..s3; lgkmcnt(0);
//    seq[w] = g+1 (volatile). Every 32 iters: WAR spin while w+1's published
//    progress < g-192 (ring lead cap 224 < 249 safe bound).
//  consumer (lane 0, wave w>0): when the slot will be used (0<=c0n<=1020),
//    spin while seq[w-1] < g-6 (producer wrote this slot at its iter g-8),
//    compiler memory barrier, then read ring.
//  Deadlock-free: wave w WAR-waits only when >=192 ahead of wave w+1, which
//  makes w+1's data-wait (needs seq >= g-6) trivially satisfied; wave 0
//  never data-waits. All flags in LDS, zeroed at kernel start (replay-safe).
__global__ __launch_bounds__(512) void nw_dp(
        const float* __restrict__ thetaT, const float* __restrict__ acc,
        const float* __restrict__ gap_b, float* __restrict__ out) {
    const int b = blockIdx.x;
    const int tid = threadIdx.x;
    const int t = tid & 63, w = tid >> 6;
    const float Ac = (acc[b] + gap_b[0]) * LOG2E;
    const int row0 = w * 128 + t * 2;          // theta rows row0, row0+1
    const int off4 = w * DSTAG + 4 * t;        // lane's column lag (cols)
    const float* Tb = thetaT + (size_t)b * NN * MM + row0;

    __shared__ float4 ring[WAVES - 1][256];
    __shared__ int seqv[WAVES];
    __shared__ int progv[WAVES];

    if (tid < WAVES) { seqv[tid] = 0; progv[tid] = 0; }
    __syncthreads();                           // once, before the main loop

    float v0 = NEGS, v1 = NEGS;
    float s0 = NEGS, s1 = NEGS, s2 = NEGS, s3 = NEGS; // bottom vals @ C..C+3
    float tpp = NEGS;                          // prev iteration's td
    float4 rt; rt.x = NEGS; rt.y = NEGS; rt.z = NEGS; rt.w = NEGS;

    float2 pf[PF][4];
    #pragma unroll
    for (int u = 0; u < PF; ++u) {
        int cn = 4 * u - off4;
        cn = cn < 0 ? 0 : cn;
        #pragma unroll
        for (int k = 0; k < 4; ++k)
            pf[u][k] = *(const float2*)(Tb + (size_t)(cn + k) * NN);
    }

    #define CELL(vk, th) {                                                   \
        float lf = vk + Ac;                                                  \
        float mx = fmaxf(fmaxf(uu, dg), lf);                                 \
        float md = __builtin_amdgcn_fmed3f(uu, dg, lf);                      \
        float mn = fminf(fminf(uu, dg), lf);                                 \
        float ss = 1.0f + __builtin_amdgcn_exp2f(md - mx)                    \
                        + __builtin_amdgcn_exp2f(mn - mx);                   \
        float l  = __builtin_amdgcn_logf(ss);                                \
        float c1 = fmaf(th, LOG2E, mx);                                      \
        dg = vk;                                                             \
        vk = l + c1;                                                         \
        uu = l + (c1 + Ac);                                                  \
    }

    for (int gg = 0; gg < GTOT; gg += PF) {
        #pragma unroll
        for (int u = 0; u < PF; ++u) {
            const int g = gg + u;
            const int C = 4 * g - off4;

            // publish progress (top of iter, before any spin)
            if (t == 0 && (g & 31) == 0) *(volatile int*)&progv[w] = g;

            float ta  = __shfl_up(s0, 1);      // V[row0][C+1] of wave above
            float tb_ = __shfl_up(s1, 1);
            float tc  = __shfl_up(s2, 1);
            float td  = __shfl_up(s3, 1);
            if (t == 0) {
                if (w == 0) { ta = NEGS; tb_ = NEGS; tc = NEGS; td = NEGS; }
                else        { ta = rt.x; tb_ = rt.y; tc = rt.z; td = rt.w; }
            }
            float tp = tpp;
            if (t == 0 && C == 0) tp = (w == 0) ? 0.0f : NEGS;
            tpp = td;

            const float2 cA = pf[u][0], cB = pf[u][1];
            const float2 cC = pf[u][2], cD = pf[u][3];
            int cn = 4 * (g + PF) - off4;
            cn = cn < 0 ? 0 : (cn > MM - 4 ? MM - 4 : cn);
            #pragma unroll
            for (int k = 0; k < 4; ++k)
                pf[u][k] = *(const float2*)(Tb + (size_t)(cn + k) * NN);

            if ((unsigned)C < MM) {
                float uu, dg;
                uu = ta + Ac;  dg = tp;  CELL(v0, cA.x) CELL(v1, cA.y) s0 = v1;
                uu = tb_ + Ac; dg = ta;  CELL(v0, cB.x) CELL(v1, cB.y) s1 = v1;
                uu = tc + Ac;  dg = tb_; CELL(v0, cC.x) CELL(v1, cC.y) s2 = v1;
                uu = td + Ac;  dg = tc;  CELL(v0, cD.x) CELL(v1, cD.y) s3 = v1;
                if (t == 63 && w < WAVES - 1) {
                    float4 pr; pr.x = s0; pr.y = s1; pr.z = s2; pr.w = s3;
                    ring[w][(C >> 2) & 255] = pr;
                    __asm__ __volatile__("s_waitcnt lgkmcnt(0)" ::: "memory");
                    *(volatile int*)&seqv[w] = g + 1;
                }
            }

            // WAR backpressure: cap lead over consumer at ~224 slots (<249)
            if (t == 63 && w < WAVES - 1 && (g & 31) == 0 && g > 192) {
                while (*(volatile int*)&progv[w + 1] < g - 192)
                    __builtin_amdgcn_s_sleep(1);
            }

            // ring prefetch for iteration g+1 (producer wrote it at iter g-8)
            if (t == 0 && w > 0) {
                int c0n = 4 * (g + 1) - w * DSTAG;
                if ((unsigned)c0n <= (unsigned)(MM - 4)) {
                    int need = g - 6;
                    while (*(volatile int*)&seqv[w - 1] < need)
                        __builtin_amdgcn_s_sleep(1);
                    __asm__ __volatile__("" ::: "memory");
                    rt = ring[w - 1][(c0n >> 2) & 255];
                }
            }
        }
    }
    #undef CELL
    if (tid == 511) out[b] = v1 * LN2f;
}

// ---------------------------------------------------------------- launcher
extern "C" void kernel_launch(void* const* d_in, const int* in_sizes, int n_in,
                              void* d_out, int out_size, void* d_ws, size_t ws_size,
                              hipStream_t stream) {
    const float* zx    = (const float*)d_in[0];
    const float* zy    = (const float*)d_in[1];
    const float* gw    = (const float*)d_in[2];
    const float* gapb  = (const float*)d_in[3];
    float* out = (float*)d_out;

    char* ws = (char*)d_ws;
    float*  thetaT = (float*)ws;                                  // 67,108,864 B
    __bf16* zxb   = (__bf16*)(ws + (size_t)67108864);             // 16,777,216 B
    __bf16* zyb   = (__bf16*)(ws + (size_t)67108864 + 16777216);  // 16,777,216 B
    float*  acc   = (float*)(ws + (size_t)67108864 + 2 * 16777216);

    zero_acc<<<1, 64, 0, stream>>>(acc);
    conv_reduce<<<dim3(16, BATCH, 2), 256, 0, stream>>>(zx, zy, gw, zxb, zyb, acc);
    // swapped args: output = theta^T
    gemm_bt<<<dim3(MM / 128, NN / 128, BATCH), 256, 0, stream>>>(zyb, zxb, thetaT);
    nw_dp<<<BATCH, 512, 0, stream>>>(thetaT, acc, gapb, out);
}

// Round 7
// 655.711 us; speedup vs baseline: 1.2061x; 1.2061x over previous
//
#include <hip/hip_runtime.h>
#include <hip/hip_bf16.h>

#define BATCH 16
#define NN 1024
#define MM 1024
#define DD 512

#define LOG2E 1.4426950408889634f
#define LN2f  0.6931471805599453f
#define NEGS  -1.442695e9f   // NEG (-1e9) scaled by log2e; acts as -inf sentinel

// DP geometry: PROVEN round-0 shape (375 us standalone): 4 waves/batch,
// 4 rows x 1 col per lane, DSTAG=128, barrier every 64, LDS ring, PF=8,
// plus the r2-proven chain cuts (single-shuffle, 1+lse3, c1 folding).
#define DSTAG 128
#define PF    8
#define GTOT  1472            // 1023 + 3*128 + 63 + 1 = 1471 -> mult of 8

typedef __bf16 v8bf __attribute__((ext_vector_type(8)));
typedef __bf16 v4bf __attribute__((ext_vector_type(4)));
typedef float  v4f  __attribute__((ext_vector_type(4)));

// ---------------------------------------------------------------- flag zero
// flags layout (ints): conv_cnt[16] | tile_cnt[16*8] | acc[16] (float bits)
__global__ void zero_flags(int* f) {
    if (threadIdx.x < 176) f[threadIdx.x] = 0;
}

// ------------------------------------------------------------- mega kernel
// bid 0..15   : DP consumer block for batch bid (4 waves).
// bid 16..527 : producer block: 1 conv chunk, then 2 GEMM 128x128 tiles.
// Cross-block protocol (cross-XCD safe):
//   producer:  __syncthreads (drains vmcnt -> stores in L2) ->
//              release fence agent (buffer_wbl2: L2 writeback) ->
//              atomicAdd(counter)  [device-scope, coherent point]
//   consumer:  relaxed agent atomic-load spin -> acquire fence agent
//              (invalidate) -> plain loads see fresh data.
// Deadlock-free: __launch_bounds__(256,4) => >=4 blocks/CU => capacity
// 1024 >= 528 blocks: ALL blocks co-resident; producers never wait on DP;
// GEMM waits only on conv done by the co-resident producer set.
__global__ __launch_bounds__(256, 4) void mega(
        const float* __restrict__ zx, const float* __restrict__ zy,
        const float* __restrict__ gw, const float* __restrict__ gap_b,
        __bf16* __restrict__ zxb, __bf16* __restrict__ zyb,
        float* __restrict__ thetaT, int* __restrict__ flags,
        float* __restrict__ out) {
    int* conv_cnt = flags;                  // [16]  (==32 when batch staged)
    int* tile_cnt = flags + 16;             // [16][8] (==8 when col-block done)
    float* acc    = (float*)(flags + 144);  // [16]

    __shared__ union {
        struct { __bf16 As[128 * 32]; __bf16 Bs[128 * 32]; } g;   // 16 KiB
        struct { float ring[3][256]; float wsum[4]; } d;          //  3 KiB
    } sm;

    const int bid = blockIdx.x;
    const int tid = threadIdx.x;

    if (bid >= 16) {
        //================= producer: conv chunk ===========================
        const int cid = bid - 16;           // 0..511
        {
            const int chunk = cid & 15, cb = (cid >> 4) & 15, which = cid >> 8;
            const float* src = which ? zy : zx;
            __bf16* dst = which ? zyb : zxb;
            const float* gwp = gw + which * DD;
            const size_t base = ((size_t)cb * NN + (size_t)chunk * 64) * DD;
            const int col = (tid * 4) & (DD - 1);
            const float4 gv = *(const float4*)(gwp + col);
            float sum = 0.0f;
            #pragma unroll 4
            for (int it = 0; it < 32; ++it) {
                size_t off = base + (size_t)it * 1024 + tid * 4;
                float4 x = *(const float4*)(src + off);
                sum += x.x * gv.x + x.y * gv.y + x.z * gv.z + x.w * gv.w;
                v4bf o = { (__bf16)x.x, (__bf16)x.y, (__bf16)x.z, (__bf16)x.w };
                *(v4bf*)(dst + off) = o;
            }
            #pragma unroll
            for (int o = 32; o > 0; o >>= 1) sum += __shfl_down(sum, o);
            if ((tid & 63) == 0) sm.d.wsum[tid >> 6] = sum;
            __syncthreads();                 // also drains the dst stores
            if (tid == 0) {
                float s = sm.d.wsum[0] + sm.d.wsum[1] + sm.d.wsum[2] + sm.d.wsum[3];
                atomicAdd(acc + cb, s * (1.0f / 1024.0f));
                __builtin_amdgcn_fence(__ATOMIC_RELEASE, "agent");
                atomicAdd(conv_cnt + cb, 1);
            }
            // NOTE: no extra barrier needed before GEMM overwrites sm:
            // LDS (As) writes only happen after the k-loop's first
            // __syncthreads, which tid0 reaches only after reading wsum.
        }
        //================= producer: 2 GEMM tiles (i-block-major order) ===
        const int lane = tid & 63, wave = tid >> 6;
        const int wr = wave >> 1, wc = wave & 1;
        const int mrow = lane & 15, quad = lane >> 4;
        const int arow = wave * 32 + (lane >> 2);
        const int acol = (lane & 3) * 8;
        #pragma unroll 1
        for (int tile = 0; tile < 2; ++tile) {
            const int T = cid + tile * 512;            // 0..1023
            const int by = T >> 7, rem = T & 127;      // by = theta col-block
            const int bb = rem >> 3, bx = rem & 7;
            // wait for batch bb fully staged (32 conv chunk-blocks)
            while (__hip_atomic_load(conv_cnt + bb, __ATOMIC_RELAXED,
                                     __HIP_MEMORY_SCOPE_AGENT) < 32)
                __builtin_amdgcn_s_sleep(8);
            __builtin_amdgcn_fence(__ATOMIC_ACQUIRE, "agent");

            const int i0 = by * 128, j0 = bx * 128;
            const __bf16* ap = zyb + ((size_t)bb * NN + i0) * DD;
            const __bf16* bp = zxb + ((size_t)bb * MM + j0) * DD;
            v4f gac[4][4] = {};
            for (int kk = 0; kk < DD; kk += 32) {
                __syncthreads();
                #pragma unroll
                for (int i = 0; i < 2; ++i) {
                    const __bf16* ga = ap + (size_t)(arow + 16 * i) * DD + kk + acol;
                    const __bf16* gb = bp + (size_t)(arow + 16 * i) * DD + kk + acol;
                    __builtin_amdgcn_global_load_lds(
                        (const __attribute__((address_space(1))) void*)ga,
                        (__attribute__((address_space(3))) void*)(sm.g.As + wave * 1024 + i * 512),
                        16, 0, 0);
                    __builtin_amdgcn_global_load_lds(
                        (const __attribute__((address_space(1))) void*)gb,
                        (__attribute__((address_space(3))) void*)(sm.g.Bs + wave * 1024 + i * 512),
                        16, 0, 0);
                }
                __syncthreads();
                v8bf af[4];
                #pragma unroll
                for (int m = 0; m < 4; ++m)
                    af[m] = *(const v8bf*)&sm.g.As[(wr * 64 + m * 16 + mrow) * 32 + quad * 8];
                #pragma unroll
                for (int n = 0; n < 4; ++n) {
                    v8bf bf = *(const v8bf*)&sm.g.Bs[(wc * 64 + n * 16 + mrow) * 32 + quad * 8];
                    #pragma unroll
                    for (int m = 0; m < 4; ++m)
                        gac[m][n] = __builtin_amdgcn_mfma_f32_16x16x32_bf16(af[m], bf, gac[m][n], 0, 0, 0);
                }
            }
            const size_t tbo = (size_t)bb * NN * MM;
            #pragma unroll
            for (int n = 0; n < 4; ++n) {
                int j = j0 + wc * 64 + n * 16 + mrow;
                #pragma unroll
                for (int m = 0; m < 4; ++m) {
                    #pragma unroll
                    for (int r = 0; r < 4; ++r) {
                        int i = i0 + wr * 64 + m * 16 + quad * 4 + r;
                        thetaT[tbo + (size_t)i * MM + j] = gac[m][n][r];
                    }
                }
            }
            __syncthreads();               // drains all waves' theta stores
            if (tid == 0) {
                __builtin_amdgcn_fence(__ATOMIC_RELEASE, "agent");
                atomicAdd(tile_cnt + bb * 8 + by, 1);
            }
        }
        return;
    }

    //================= DP consumer block (batch = bid) ====================
    const int bb = bid;
    const int t = tid & 63, w = tid >> 6;
    // startup: first theta col-block (implies conv + acc final for bb)
    while (__hip_atomic_load(tile_cnt + bb * 8, __ATOMIC_RELAXED,
                             __HIP_MEMORY_SCOPE_AGENT) < 8)
        __builtin_amdgcn_s_sleep(32);
    __builtin_amdgcn_fence(__ATOMIC_ACQUIRE, "agent");

    const float Ac = (acc[bb] + gap_b[0]) * LOG2E;
    const int row0 = w * 256 + t * 4;
    const int off = w * DSTAG + t;
    const float* Tb = thetaT + (size_t)bb * NN * MM + row0;

    float v[4];
    v[0] = v[1] = v[2] = v[3] = NEGS;
    float v3c = NEGS;                       // bottom-row value, prev iter
    float tcp = NEGS;                       // prev iteration's tc (post-fixup)
    float rtc = NEGS;                       // prefetched ring value (lane 0)

    float4 pfr[PF];
    #pragma unroll
    for (int u = 0; u < PF; ++u) {
        int c0 = u - off;
        c0 = c0 < 0 ? 0 : c0;               // cols 0..7: covered by block 0
        pfr[u] = *(const float4*)(Tb + (size_t)c0 * NN);
    }

    int last_ready = 1;                     // col-blocks [0,last_ready) ready
    for (int gg = 0; gg < GTOT; gg += PF) {
        // progressive availability: window [gg,gg+8) touches cols <= gg+15
        if (last_ready < 8) {
            int need = (gg + 15) >> 7;
            if (need > 7) need = 7;
            if (need >= last_ready) {
                while (__hip_atomic_load(tile_cnt + bb * 8 + need, __ATOMIC_RELAXED,
                                         __HIP_MEMORY_SCOPE_AGENT) < 8)
                    __builtin_amdgcn_s_sleep(16);
                __builtin_amdgcn_fence(__ATOMIC_ACQUIRE, "agent");
                last_ready = need + 1;
            }
        }
        #pragma unroll
        for (int u = 0; u < PF; ++u) {
            const int g = gg + u;
            const int c = g - off;

            float tc = __shfl_up(v3c, 1);   // up input: neighbor bottom @ c
            if (t == 0) tc = (w == 0) ? NEGS : rtc;
            float tp = tcp;                 // diag input: prev iteration's tc
            if (t == 0 && c == 0) tp = (w == 0) ? 0.0f : NEGS;
            tcp = tc;

            const float4 cur = pfr[u];
            int cn = g + PF - off;
            cn = cn < 0 ? 0 : (cn > MM - 1 ? MM - 1 : cn);
            pfr[u] = *(const float4*)(Tb + (size_t)cn * NN);

            if ((unsigned)c < MM) {
                const float* th = (const float*)&cur;
                float lfA0 = v[0] + Ac, lfA1 = v[1] + Ac;
                float lfA2 = v[2] + Ac, lfA3 = v[3] + Ac;
                float uu = tc + Ac;
                float dg = tp;
                #pragma unroll
                for (int k = 0; k < 4; ++k) {
                    float lf = k == 0 ? lfA0 : (k == 1 ? lfA1 : (k == 2 ? lfA2 : lfA3));
                    float mx = fmaxf(fmaxf(uu, dg), lf);
                    float md = __builtin_amdgcn_fmed3f(uu, dg, lf);
                    float mn = fminf(fminf(uu, dg), lf);
                    float ss = 1.0f + __builtin_amdgcn_exp2f(md - mx)
                                    + __builtin_amdgcn_exp2f(mn - mx);
                    float l  = __builtin_amdgcn_logf(ss);
                    float c1 = fmaf(th[k], LOG2E, mx);
                    float nd = v[k];
                    v[k] = l + c1;
                    uu   = l + (c1 + Ac);
                    dg = nd;
                }
                v3c = v[3];
                if (t == 63 && w < 3) sm.d.ring[w][c & 255] = v[3];
            }

            if ((g & 63) == 63) __syncthreads();

            // ring prefetch for iteration g+1 (producer wrote the column 64
            // iterations earlier; exactly one barrier strictly between).
            if (t == 0 && w > 0) {
                int cnx = g + 1 - off;
                rtc = sm.d.ring[w - 1][cnx & 255];
            }
        }
    }
    if (tid == 255) out[bb] = v[3] * LN2f;
}

// ---------------------------------------------------------------- launcher
extern "C" void kernel_launch(void* const* d_in, const int* in_sizes, int n_in,
                              void* d_out, int out_size, void* d_ws, size_t ws_size,
                              hipStream_t stream) {
    const float* zx    = (const float*)d_in[0];
    const float* zy    = (const float*)d_in[1];
    const float* gw    = (const float*)d_in[2];
    const float* gapb  = (const float*)d_in[3];
    float* out = (float*)d_out;

    char* ws = (char*)d_ws;
    float*  thetaT = (float*)ws;                                  // 67,108,864 B
    __bf16* zxb   = (__bf16*)(ws + (size_t)67108864);             // 16,777,216 B
    __bf16* zyb   = (__bf16*)(ws + (size_t)67108864 + 16777216);  // 16,777,216 B
    int*    flags = (int*)(ws + (size_t)67108864 + 2 * 16777216); // 704 B

    zero_flags<<<1, 256, 0, stream>>>(flags);
    mega<<<528, 256, 0, stream>>>(zx, zy, gw, gapb, zxb, zyb, thetaT, flags, out);
}

// Round 8
// 583.826 us; speedup vs baseline: 1.3546x; 1.1231x over previous
//
#include <hip/hip_runtime.h>
#include <hip/hip_bf16.h>

#define BATCH 16
#define NN 1024
#define MM 1024
#define DD 512

#define LOG2E 1.4426950408889634f
#define LN2f  0.6931471805599453f
#define NEGS  -1.442695e9f   // NEG (-1e9) scaled by log2e; acts as -inf sentinel

// DP geometry: PROVEN round-0 shape (375 us standalone): 4 waves/batch,
// 4 rows x 1 col per lane, DSTAG=128, barrier every 64, LDS ring, PF=8,
// plus the r2/r7-proven chain cuts (single-shuffle, 1+lse3, c1 folding).
#define DSTAG 128
#define PF    8
#define GTOT  1472            // 1023 + 3*128 + 63 + 1 = 1471 -> mult of 8

#define NPROD 240             // producer blocks; grid = 16 DP + 240 = 256 = #CUs

typedef __bf16 v8bf __attribute__((ext_vector_type(8)));
typedef __bf16 v4bf __attribute__((ext_vector_type(4)));
typedef float  v4f  __attribute__((ext_vector_type(4)));

// ---------------------------------------------------------------- flag zero
// flags layout (ints): conv_cnt[16] | tile_cnt[16*8] | acc[16] (float bits)
__global__ void zero_flags(int* f) {
    if (threadIdx.x < 176) f[threadIdx.x] = 0;
}

// ------------------------------------------------------------- mega kernel
// ONE block per CU (grid 256 = #CUs): DP blocks (bid 0..15) get dedicated
// CUs -> the latency-critical DP chain runs unstretched (r7 showed 4 blk/CU
// sharing stretches it 1.3x). Producers (bid 16..255) are persistent: 2-3
// conv chunks each, then 4-5 GEMM 128x128 tiles each, tile stride NPROD so
// tiles 0..127 (= col-block 0 of every batch) complete first.
// Cross-block protocol (verified absmax-0 in r7):
//   producer:  __syncthreads (drains stores) -> release fence agent ->
//              atomicAdd(counter)
//   consumer:  relaxed agent atomic-load spin -> acquire fence agent -> read.
// Deadlock-free: 256 blocks trivially all-resident; producers never wait on
// DP; GEMM waits only on conv counters that producers complete unconditionally.
__global__ __launch_bounds__(256, 4) void mega(
        const float* __restrict__ zx, const float* __restrict__ zy,
        const float* __restrict__ gw, const float* __restrict__ gap_b,
        __bf16* __restrict__ zxb, __bf16* __restrict__ zyb,
        float* __restrict__ thetaT, int* __restrict__ flags,
        float* __restrict__ out) {
    int* conv_cnt = flags;                  // [16]  (==32 when batch staged)
    int* tile_cnt = flags + 16;             // [16][8] (==8 when col-block done)
    float* acc    = (float*)(flags + 144);  // [16]

    __shared__ union {
        struct { __bf16 As[128 * 32]; __bf16 Bs[128 * 32]; } g;   // 16 KiB
        struct { float ring[3][256]; float wsum[4]; } d;          //  3 KiB
    } sm;

    const int bid = blockIdx.x;
    const int tid = threadIdx.x;

    if (bid >= 16) {
        const int p = bid - 16;             // 0..239
        //================= producer: conv chunks ==========================
        for (int cidx = p; cidx < 512; cidx += NPROD) {
            const int chunk = cidx & 15, cb = (cidx >> 4) & 15, which = cidx >> 8;
            const float* src = which ? zy : zx;
            __bf16* dst = which ? zyb : zxb;
            const float* gwp = gw + which * DD;
            const size_t base = ((size_t)cb * NN + (size_t)chunk * 64) * DD;
            const int col = (tid * 4) & (DD - 1);
            const float4 gv = *(const float4*)(gwp + col);
            float sum = 0.0f;
            #pragma unroll 4
            for (int it = 0; it < 32; ++it) {
                size_t off = base + (size_t)it * 1024 + tid * 4;
                float4 x = *(const float4*)(src + off);
                sum += x.x * gv.x + x.y * gv.y + x.z * gv.z + x.w * gv.w;
                v4bf o = { (__bf16)x.x, (__bf16)x.y, (__bf16)x.z, (__bf16)x.w };
                *(v4bf*)(dst + off) = o;
            }
            #pragma unroll
            for (int o = 32; o > 0; o >>= 1) sum += __shfl_down(sum, o);
            if ((tid & 63) == 0) sm.d.wsum[tid >> 6] = sum;
            __syncthreads();                 // also drains the dst stores
            if (tid == 0) {
                float s = sm.d.wsum[0] + sm.d.wsum[1] + sm.d.wsum[2] + sm.d.wsum[3];
                atomicAdd(acc + cb, s * (1.0f / 1024.0f));
                __builtin_amdgcn_fence(__ATOMIC_RELEASE, "agent");
                atomicAdd(conv_cnt + cb, 1);
            }
            __syncthreads();                 // wsum reuse guard (loop)
        }
        //================= producer: GEMM tiles (col-block-major) =========
        const int lane = tid & 63, wave = tid >> 6;
        const int wr = wave >> 1, wc = wave & 1;
        const int mrow = lane & 15, quad = lane >> 4;
        const int arow = wave * 32 + (lane >> 2);
        const int acol = (lane & 3) * 8;
        #pragma unroll 1
        for (int T = p; T < 1024; T += NPROD) {
            const int by = T >> 7, rem = T & 127;      // by = DP col-block
            const int bb = rem >> 3, bx = rem & 7;
            while (__hip_atomic_load(conv_cnt + bb, __ATOMIC_RELAXED,
                                     __HIP_MEMORY_SCOPE_AGENT) < 32)
                __builtin_amdgcn_s_sleep(8);
            __builtin_amdgcn_fence(__ATOMIC_ACQUIRE, "agent");

            const int i0 = by * 128, j0 = bx * 128;
            const __bf16* ap = zyb + ((size_t)bb * NN + i0) * DD;
            const __bf16* bp = zxb + ((size_t)bb * MM + j0) * DD;
            v4f gac[4][4] = {};
            for (int kk = 0; kk < DD; kk += 32) {
                __syncthreads();
                #pragma unroll
                for (int i = 0; i < 2; ++i) {
                    const __bf16* ga = ap + (size_t)(arow + 16 * i) * DD + kk + acol;
                    const __bf16* gb = bp + (size_t)(arow + 16 * i) * DD + kk + acol;
                    __builtin_amdgcn_global_load_lds(
                        (const __attribute__((address_space(1))) void*)ga,
                        (__attribute__((address_space(3))) void*)(sm.g.As + wave * 1024 + i * 512),
                        16, 0, 0);
                    __builtin_amdgcn_global_load_lds(
                        (const __attribute__((address_space(1))) void*)gb,
                        (__attribute__((address_space(3))) void*)(sm.g.Bs + wave * 1024 + i * 512),
                        16, 0, 0);
                }
                __syncthreads();
                v8bf af[4];
                #pragma unroll
                for (int m = 0; m < 4; ++m)
                    af[m] = *(const v8bf*)&sm.g.As[(wr * 64 + m * 16 + mrow) * 32 + quad * 8];
                #pragma unroll
                for (int n = 0; n < 4; ++n) {
                    v8bf bf = *(const v8bf*)&sm.g.Bs[(wc * 64 + n * 16 + mrow) * 32 + quad * 8];
                    #pragma unroll
                    for (int m = 0; m < 4; ++m)
                        gac[m][n] = __builtin_amdgcn_mfma_f32_16x16x32_bf16(af[m], bf, gac[m][n], 0, 0, 0);
                }
            }
            const size_t tbo = (size_t)bb * NN * MM;
            #pragma unroll
            for (int n = 0; n < 4; ++n) {
                int j = j0 + wc * 64 + n * 16 + mrow;
                #pragma unroll
                for (int m = 0; m < 4; ++m) {
                    #pragma unroll
                    for (int r = 0; r < 4; ++r) {
                        int i = i0 + wr * 64 + m * 16 + quad * 4 + r;
                        thetaT[tbo + (size_t)i * MM + j] = gac[m][n][r];
                    }
                }
            }
            __syncthreads();               // drains all waves' theta stores
            if (tid == 0) {
                __builtin_amdgcn_fence(__ATOMIC_RELEASE, "agent");
                atomicAdd(tile_cnt + bb * 8 + by, 1);
            }
        }
        return;
    }

    //================= DP consumer block (batch = bid) ====================
    const int bb = bid;
    const int t = tid & 63, w = tid >> 6;
    // startup: first theta col-block (implies conv + acc final for bb)
    while (__hip_atomic_load(tile_cnt + bb * 8, __ATOMIC_RELAXED,
                             __HIP_MEMORY_SCOPE_AGENT) < 8)
        __builtin_amdgcn_s_sleep(32);
    __builtin_amdgcn_fence(__ATOMIC_ACQUIRE, "agent");

    const float Ac = (acc[bb] + gap_b[0]) * LOG2E;
    const int row0 = w * 256 + t * 4;
    const int off = w * DSTAG + t;
    const float* Tb = thetaT + (size_t)bb * NN * MM + row0;

    float v[4];
    v[0] = v[1] = v[2] = v[3] = NEGS;
    float v3c = NEGS;                       // bottom-row value, prev iter
    float tcp = NEGS;                       // prev iteration's tc (post-fixup)
    float rtc = NEGS;                       // prefetched ring value (lane 0)

    float4 pfr[PF];
    #pragma unroll
    for (int u = 0; u < PF; ++u) {
        int c0 = u - off;
        c0 = c0 < 0 ? 0 : c0;               // cols 0..7: covered by block 0
        pfr[u] = *(const float4*)(Tb + (size_t)c0 * NN);
    }

    int last_ready = 1;                     // col-blocks [0,last_ready) ready
    for (int gg = 0; gg < GTOT; gg += PF) {
        // progressive availability: window [gg,gg+8) touches cols <= gg+15
        if (last_ready < 8) {
            int need = (gg + 15) >> 7;
            if (need > 7) need = 7;
            if (need >= last_ready) {
                while (__hip_atomic_load(tile_cnt + bb * 8 + need, __ATOMIC_RELAXED,
                                         __HIP_MEMORY_SCOPE_AGENT) < 8)
                    __builtin_amdgcn_s_sleep(16);
                __builtin_amdgcn_fence(__ATOMIC_ACQUIRE, "agent");
                last_ready = need + 1;
            }
        }
        #pragma unroll
        for (int u = 0; u < PF; ++u) {
            const int g = gg + u;
            const int c = g - off;

            float tc = __shfl_up(v3c, 1);   // up input: neighbor bottom @ c
            if (t == 0) tc = (w == 0) ? NEGS : rtc;
            float tp = tcp;                 // diag input: prev iteration's tc
            if (t == 0 && c == 0) tp = (w == 0) ? 0.0f : NEGS;
            tcp = tc;

            const float4 cur = pfr[u];
            int cn = g + PF - off;
            cn = cn < 0 ? 0 : (cn > MM - 1 ? MM - 1 : cn);
            pfr[u] = *(const float4*)(Tb + (size_t)cn * NN);

            if ((unsigned)c < MM) {
                const float* th = (const float*)&cur;
                float lfA0 = v[0] + Ac, lfA1 = v[1] + Ac;
                float lfA2 = v[2] + Ac, lfA3 = v[3] + Ac;
                float uu = tc + Ac;
                float dg = tp;
                #pragma unroll
                for (int k = 0; k < 4; ++k) {
                    float lf = k == 0 ? lfA0 : (k == 1 ? lfA1 : (k == 2 ? lfA2 : lfA3));
                    float mx = fmaxf(fmaxf(uu, dg), lf);
                    float md = __builtin_amdgcn_fmed3f(uu, dg, lf);
                    float mn = fminf(fminf(uu, dg), lf);
                    float ss = 1.0f + __builtin_amdgcn_exp2f(md - mx)
                                    + __builtin_amdgcn_exp2f(mn - mx);
                    float l  = __builtin_amdgcn_logf(ss);
                    float c1 = fmaf(th[k], LOG2E, mx);
                    float nd = v[k];
                    v[k] = l + c1;
                    uu   = l + (c1 + Ac);
                    dg = nd;
                }
                v3c = v[3];
                if (t == 63 && w < 3) sm.d.ring[w][c & 255] = v[3];
            }

            if ((g & 63) == 63) __syncthreads();

            // ring prefetch for iteration g+1 (producer wrote the column 64
            // iterations earlier; exactly one barrier strictly between).
            if (t == 0 && w > 0) {
                int cnx = g + 1 - off;
                rtc = sm.d.ring[w - 1][cnx & 255];
            }
        }
    }
    if (tid == 255) out[bb] = v[3] * LN2f;
}

// ---------------------------------------------------------------- launcher
extern "C" void kernel_launch(void* const* d_in, const int* in_sizes, int n_in,
                              void* d_out, int out_size, void* d_ws, size_t ws_size,
                              hipStream_t stream) {
    const float* zx    = (const float*)d_in[0];
    const float* zy    = (const float*)d_in[1];
    const float* gw    = (const float*)d_in[2];
    const float* gapb  = (const float*)d_in[3];
    float* out = (float*)d_out;

    char* ws = (char*)d_ws;
    float*  thetaT = (float*)ws;                                  // 67,108,864 B
    __bf16* zxb   = (__bf16*)(ws + (size_t)67108864);             // 16,777,216 B
    __bf16* zyb   = (__bf16*)(ws + (size_t)67108864 + 16777216);  // 16,777,216 B
    int*    flags = (int*)(ws + (size_t)67108864 + 2 * 16777216); // 704 B

    zero_flags<<<1, 256, 0, stream>>>(flags);
    mega<<<16 + NPROD, 256, 0, stream>>>(zx, zy, gw, gapb, zxb, zyb, thetaT, flags, out);
}

// Round 9
// 488.431 us; speedup vs baseline: 1.6191x; 1.1953x over previous
//
#include <hip/hip_runtime.h>
#include <hip/hip_bf16.h>

#define BATCH 16
#define NN 1024
#define MM 1024
#define DD 512

#define LOG2E 1.4426950408889634f
#define LN2f  0.6931471805599453f
#define NEGS  -1.442695e9f   // NEG (-1e9) scaled by log2e; acts as -inf sentinel

// nw_dp geometry: PROVEN round-0 shell (16 blocks x 256 thr, 4 waves,
// 4 rows x 1 col per lane, LDS ring) with two additions:
//  - r2/r7/r8-proven chain cuts (single-shuffle, "1+" lse3, c1 folding)
//  - skew cut: barrier every 32 iters (was 64) allows DSTAG 128 -> 96.
//    Invariant preserved: producer (lane63,wave w) writes col c at iter
//    c+96w+63; consumer (lane0,wave w+1) prefetch-reads at iter c+96w+96,
//    gap 33 > 32 => >=1 barrier strictly between write and read. Ring WAR:
//    slot reused 256 iters after write, read at +33 => margin 223.
#define DSTAG 96
#define PF    8
#define GTOT  1376            // g_last = 1023 + 3*96 + 63 = 1374; mult of 32

typedef __bf16 v8bf __attribute__((ext_vector_type(8)));
typedef __bf16 v4bf __attribute__((ext_vector_type(4)));
typedef float  v4f  __attribute__((ext_vector_type(4)));

// ---------------------------------------------------------------- zero A acc
__global__ void zero_acc(float* a) {
    if (threadIdx.x < BATCH) a[threadIdx.x] = 0.0f;
}

// ------------------------------------------- fp32->bf16 convert + gap-dot
__global__ __launch_bounds__(256) void conv_reduce(
        const float* __restrict__ zx, const float* __restrict__ zy,
        const float* __restrict__ gw,
        __bf16* __restrict__ zxb, __bf16* __restrict__ zyb,
        float* __restrict__ acc) {
    const int chunk = blockIdx.x, b = blockIdx.y, which = blockIdx.z;
    const float* src = which ? zy : zx;
    __bf16* dst = which ? zyb : zxb;
    const float* g = gw + which * DD;
    const size_t base = ((size_t)b * NN + (size_t)chunk * 64) * DD;
    const int t = threadIdx.x;
    const int col = (t * 4) & (DD - 1);
    const float4 gv = *(const float4*)(g + col);
    float sum = 0.0f;
    #pragma unroll 4
    for (int it = 0; it < 32; ++it) {
        size_t off = base + (size_t)it * 1024 + t * 4;
        float4 x = *(const float4*)(src + off);
        sum += x.x * gv.x + x.y * gv.y + x.z * gv.z + x.w * gv.w;
        v4bf o = { (__bf16)x.x, (__bf16)x.y, (__bf16)x.z, (__bf16)x.w };
        *(v4bf*)(dst + off) = o;
    }
    #pragma unroll
    for (int o = 32; o > 0; o >>= 1) sum += __shfl_down(sum, o);
    __shared__ float wsum[4];
    if ((t & 63) == 0) wsum[t >> 6] = sum;
    __syncthreads();
    if (t == 0) {
        float s = wsum[0] + wsum[1] + wsum[2] + wsum[3];
        atomicAdd(acc + b, s * (1.0f / 1024.0f));
    }
}

// ------------------------------------------------------- bf16 MFMA NT GEMM
// m97-structure (verified absmax-0 in r5/r7/r8): 128x128 tile, 4 waves 2x2,
// 4x4 16x16x32 MFMA frags, BK=32, global_load_lds width 16, linear LDS.
// out[row i][col j] = sum_d A[i,d]*B[j,d]. Called with A=zyb, B=zxb so the
// output buffer is thetaT (theta transposed) at zero cost.
__global__ __launch_bounds__(256) void gemm_bt(
        const __bf16* __restrict__ Abf, const __bf16* __restrict__ Bbf,
        float* __restrict__ theta) {
    __shared__ __bf16 As[128 * 32];
    __shared__ __bf16 Bs[128 * 32];
    const int b = blockIdx.z;
    const int i0 = blockIdx.y * 128, j0 = blockIdx.x * 128;
    const __bf16* ap = Abf + ((size_t)b * NN + i0) * DD;
    const __bf16* bp = Bbf + ((size_t)b * MM + j0) * DD;
    const int t = threadIdx.x;
    const int lane = t & 63, wave = t >> 6;
    const int wr = wave >> 1, wc = wave & 1;
    const int mrow = lane & 15, quad = lane >> 4;
    const int arow = wave * 32 + (lane >> 2);
    const int acol = (lane & 3) * 8;
    v4f acc[4][4] = {};
    for (int kk = 0; kk < DD; kk += 32) {
        __syncthreads();
        #pragma unroll
        for (int i = 0; i < 2; ++i) {
            const __bf16* ga = ap + (size_t)(arow + 16 * i) * DD + kk + acol;
            const __bf16* gb = bp + (size_t)(arow + 16 * i) * DD + kk + acol;
            __builtin_amdgcn_global_load_lds(
                (const __attribute__((address_space(1))) void*)ga,
                (__attribute__((address_space(3))) void*)(As + wave * 1024 + i * 512),
                16, 0, 0);
            __builtin_amdgcn_global_load_lds(
                (const __attribute__((address_space(1))) void*)gb,
                (__attribute__((address_space(3))) void*)(Bs + wave * 1024 + i * 512),
                16, 0, 0);
        }
        __syncthreads();
        v8bf af[4];
        #pragma unroll
        for (int m = 0; m < 4; ++m)
            af[m] = *(const v8bf*)&As[(wr * 64 + m * 16 + mrow) * 32 + quad * 8];
        #pragma unroll
        for (int n = 0; n < 4; ++n) {
            v8bf bf = *(const v8bf*)&Bs[(wc * 64 + n * 16 + mrow) * 32 + quad * 8];
            #pragma unroll
            for (int m = 0; m < 4; ++m)
                acc[m][n] = __builtin_amdgcn_mfma_f32_16x16x32_bf16(af[m], bf, acc[m][n], 0, 0, 0);
        }
    }
    const size_t tb = (size_t)b * NN * MM;
    #pragma unroll
    for (int n = 0; n < 4; ++n) {
        int j = j0 + wc * 64 + n * 16 + mrow;
        #pragma unroll
        for (int m = 0; m < 4; ++m) {
            #pragma unroll
            for (int r = 0; r < 4; ++r) {
                int i = i0 + wr * 64 + m * 16 + quad * 4 + r;
                theta[tb + (size_t)i * MM + j] = acc[m][n][r];
            }
        }
    }
}

// --------------------------------------------------- soft-NW wavefront DP
// 4 waves per batch (256 threads). Wave w owns V-rows 256w+1..256w+256, lane
// owns 4 rows x 1 col per iteration. DSTAG=96, barrier every 32 (see top).
// Chain cuts (verified absmax-0 in r2/r7/r8):
//  - single-shuffle: diag input tp at iter g == post-fixup tc of iter g-1
//  - "1+" lse3: ss = 1 + exp2(med-mx) + exp2(mn-mx) via max3/med3/min3
//  - c1 folding: c1 = fma(th,log2e,mx) off-chain; uu = l + (c1+Ac)
__global__ __launch_bounds__(256) void nw_dp(
        const float* __restrict__ thetaT, const float* __restrict__ acc,
        const float* __restrict__ gap_b, float* __restrict__ out) {
    const int b = blockIdx.x;
    const int tid = threadIdx.x;
    const int t = tid & 63, w = tid >> 6;
    const float Ac = (acc[b] + gap_b[0]) * LOG2E;
    const int row0 = w * 256 + t * 4;          // theta rows row0..row0+3
    const int off = w * DSTAG + t;             // lane's column lag
    const float* Tb = thetaT + (size_t)b * NN * MM + row0;

    __shared__ float ring[3][256];

    float v[4];
    v[0] = v[1] = v[2] = v[3] = NEGS;
    float v3c = NEGS;                          // bottom-row value, prev iter
    float tcp = NEGS;                          // prev iteration's tc (post-fixup)
    float rtc = NEGS;                          // prefetched ring value (lane 0)

    float4 pfr[PF];
    #pragma unroll
    for (int u = 0; u < PF; ++u) {
        int c0 = u - off;
        c0 = c0 < 0 ? 0 : c0;                  // u-off <= 7 < MM: low clamp only
        pfr[u] = *(const float4*)(Tb + (size_t)c0 * NN);
    }

    for (int gg = 0; gg < GTOT; gg += PF) {
        #pragma unroll
        for (int u = 0; u < PF; ++u) {
            const int g = gg + u;
            const int c = g - off;

            float tc = __shfl_up(v3c, 1);      // up input: neighbor bottom @ c
            if (t == 0) tc = (w == 0) ? NEGS : rtc;
            float tp = tcp;                    // diag input: prev iteration's tc
            if (t == 0 && c == 0) tp = (w == 0) ? 0.0f : NEGS;
            tcp = tc;

            const float4 cur = pfr[u];
            int cn = g + PF - off;             // re-issue this slot: col g+PF
            cn = cn < 0 ? 0 : (cn > MM - 1 ? MM - 1 : cn);
            pfr[u] = *(const float4*)(Tb + (size_t)cn * NN);

            if ((unsigned)c < MM) {
                const float* th = (const float*)&cur;
                float lfA0 = v[0] + Ac, lfA1 = v[1] + Ac;
                float lfA2 = v[2] + Ac, lfA3 = v[3] + Ac;
                float uu = tc + Ac;
                float dg = tp;
                #pragma unroll
                for (int k = 0; k < 4; ++k) {
                    float lf = k == 0 ? lfA0 : (k == 1 ? lfA1 : (k == 2 ? lfA2 : lfA3));
                    float mx = fmaxf(fmaxf(uu, dg), lf);
                    float md = __builtin_amdgcn_fmed3f(uu, dg, lf);
                    float mn = fminf(fminf(uu, dg), lf);
                    float ss = 1.0f + __builtin_amdgcn_exp2f(md - mx)
                                    + __builtin_amdgcn_exp2f(mn - mx);
                    float l  = __builtin_amdgcn_logf(ss);
                    float c1 = fmaf(th[k], LOG2E, mx);
                    float nd = v[k];
                    v[k] = l + c1;
                    uu   = l + (c1 + Ac);
                    dg = nd;
                }
                v3c = v[3];
                if (t == 63 && w < 3) ring[w][c & 255] = v[3];
            }

            if ((g & 31) == 31) __syncthreads();

            // ring prefetch for iteration g+1 (producer wrote the column 33
            // iterations earlier; >=1 barrier strictly between).
            if (t == 0 && w > 0) {
                int cnx = g + 1 - off;
                rtc = ring[w - 1][cnx & 255];
            }
        }
    }
    if (tid == 255) out[b] = v[3] * LN2f;
}

// ---------------------------------------------------------------- launcher
extern "C" void kernel_launch(void* const* d_in, const int* in_sizes, int n_in,
                              void* d_out, int out_size, void* d_ws, size_t ws_size,
                              hipStream_t stream) {
    const float* zx    = (const float*)d_in[0];
    const float* zy    = (const float*)d_in[1];
    const float* gw    = (const float*)d_in[2];
    const float* gapb  = (const float*)d_in[3];
    float* out = (float*)d_out;

    char* ws = (char*)d_ws;
    float*  thetaT = (float*)ws;                                  // 67,108,864 B
    __bf16* zxb   = (__bf16*)(ws + (size_t)67108864);             // 16,777,216 B
    __bf16* zyb   = (__bf16*)(ws + (size_t)67108864 + 16777216);  // 16,777,216 B
    float*  acc   = (float*)(ws + (size_t)67108864 + 2 * 16777216);

    zero_acc<<<1, 64, 0, stream>>>(acc);
    conv_reduce<<<dim3(16, BATCH, 2), 256, 0, stream>>>(zx, zy, gw, zxb, zyb, acc);
    // swapped args: output = theta^T
    gemm_bt<<<dim3(MM / 128, NN / 128, BATCH), 256, 0, stream>>>(zyb, zxb, thetaT);
    nw_dp<<<BATCH, 256, 0, stream>>>(thetaT, acc, gapb, out);
}